// Round 6
// baseline (76.516 us; speedup 1.0000x reference)
//
#include <hip/hip_runtime.h>
#include <math.h>

#define B_DIM    1024
#define IN_DIMS  512
#define OUT_DIMS 512
#define MOD_DIM  256
#define EPS_F    1e-8f

typedef __attribute__((ext_vector_type(8))) short bf16x8;
typedef __attribute__((ext_vector_type(4))) float f32x4;

__device__ __forceinline__ unsigned short f2bf(float f) {
    union { float f; unsigned u; } c; c.f = f;
    unsigned r = c.u + 0x7fffu + ((c.u >> 16) & 1u);   // RNE
    return (unsigned short)(r >> 16);
}
__device__ __forceinline__ float bf2f(unsigned short h) {
    union { float f; unsigned u; } c; c.u = ((unsigned)h) << 16;
    return c.f;
}

// async 16B/lane global->LDS (wave covers 64*16B = 1024B)
__device__ __forceinline__ void gload_lds16(const void* g, void* l) {
    __builtin_amdgcn_global_load_lds(
        (const __attribute__((address_space(1))) unsigned int*)g,
        (__attribute__((address_space(3))) unsigned int*)l, 16, 0, 0);
}

// ---------------------------------------------------------------------------
// Round 6: move ALL conversion/reduction prep into k0 (full-device parallel);
// k1 becomes k2-shaped (pure async stage -> 1 barrier -> MFMA -> epilogue).
//
// ws layout (bytes):
//   t_bf @ 0       1 MB    [1024,512] bf16 (linear)
//   wbf  @ 1.0 MB  0.5 MB  [512,512]  bf16 (linear)
//   AhP  @ 1.5 MB  0.5 MB  [1024,256] bf16 hi(mods), row-XOR-swizzled
//   AlP  @ 2.0 MB  0.5 MB  lo(mods)
//   BhP  @ 2.5 MB  .25 MB  [512,256]  hi(mod_w)
//   BlP  @ 2.75MB  .25 MB  lo(mod_w)
//   csp  @ 3.0 MB  16 KB   [8][512] f32 colsum partials
//
// Plane swizzle (Guideline 21: swizzled source + linear gload_lds dest +
// swizzled LDS read): 512B rows; 16B chunk c of row r stored at chunk
// c ^ (r&7). k1 reads ds_read_b128 at rows wm/wn+lr (stride 512B = bank-
// aliased) -> XOR spreads 8 lanes over all 32 banks, 2-way alias = free.
// ---------------------------------------------------------------------------

__global__ __launch_bounds__(256) void k0_prep(
    const float* __restrict__ weight,  // [512,512]
    const float* __restrict__ mods,    // [1024,256]
    const float* __restrict__ mod_w,   // [512,256]
    unsigned short* __restrict__ wbf,
    unsigned short* __restrict__ AhP, unsigned short* __restrict__ AlP,
    unsigned short* __restrict__ BhP, unsigned short* __restrict__ BlP,
    float* __restrict__ csp)
{
    __shared__ float4 csm[32][8];
    const int tid = threadIdx.x;
    const int bid = blockIdx.x;

    if (bid < 128) {
        // ---- colsum partials: cols g*32..+31, rows p*64..+63 ----
        const int g = bid & 15, p = bid >> 4;
        const int c4 = tid & 7, rr = tid >> 3;
        float4 acc = {0.f, 0.f, 0.f, 0.f};
        #pragma unroll
        for (int it = 0; it < 2; it++) {
            const int row = p * 64 + rr + 32 * it;
            float4 v = *(const float4*)&weight[row * IN_DIMS + g * 32 + c4 * 4];
            acc.x += v.x * v.x; acc.y += v.y * v.y;
            acc.z += v.z * v.z; acc.w += v.w * v.w;
        }
        csm[rr][c4] = acc;
        __syncthreads();
        if (tid < 8) {
            float4 s = csm[0][tid];
            #pragma unroll
            for (int j = 1; j < 32; j++) {
                float4 v = csm[j][tid];
                s.x += v.x; s.y += v.y; s.z += v.z; s.w += v.w;
            }
            *(float4*)&csp[p * 512 + g * 32 + tid * 4] = s;
        }
    } else if (bid < 384) {
        // ---- weight fp32 -> bf16 (linear), 2 rows/block ----
        const int row = (bid - 128) * 2 + (tid >> 7);
        const int c4 = tid & 127;
        float4 v = *(const float4*)&weight[row * IN_DIMS + c4 * 4];
        ushort4 h;
        h.x = f2bf(v.x); h.y = f2bf(v.y); h.z = f2bf(v.z); h.w = f2bf(v.w);
        *(ushort4*)&wbf[row * IN_DIMS + c4 * 4] = h;
    } else if (bid < 640) {
        // ---- mods split hi/lo -> swizzled planes, 1 float4/thread ----
        const int f = (bid - 384) * 256 + tid;      // [0, 65536)
        const int r = f >> 6, c4 = f & 63;
        float4 v = *(const float4*)&mods[r * MOD_DIM + c4 * 4];
        ushort4 h, l;
        h.x = f2bf(v.x); l.x = f2bf(v.x - bf2f(h.x));
        h.y = f2bf(v.y); l.y = f2bf(v.y - bf2f(h.y));
        h.z = f2bf(v.z); l.z = f2bf(v.z - bf2f(h.z));
        h.w = f2bf(v.w); l.w = f2bf(v.w - bf2f(h.w));
        // chunk = c4>>1 (16B); swizzled short-offset within row:
        const int sw = ((((c4 >> 1) ^ (r & 7)) << 3) + (c4 & 1) * 4);
        *(ushort4*)&AhP[r * 256 + sw] = h;
        *(ushort4*)&AlP[r * 256 + sw] = l;
    } else {
        // ---- mod_w split hi/lo -> swizzled planes ----
        const int f = (bid - 640) * 256 + tid;      // [0, 32768)
        const int r = f >> 6, c4 = f & 63;
        float4 v = *(const float4*)&mod_w[r * MOD_DIM + c4 * 4];
        ushort4 h, l;
        h.x = f2bf(v.x); l.x = f2bf(v.x - bf2f(h.x));
        h.y = f2bf(v.y); l.y = f2bf(v.y - bf2f(h.y));
        h.z = f2bf(v.z); l.z = f2bf(v.z - bf2f(h.z));
        h.w = f2bf(v.w); l.w = f2bf(v.w - bf2f(h.w));
        const int sw = ((((c4 >> 1) ^ (r & 7)) << 3) + (c4 & 1) * 4);
        *(ushort4*)&BhP[r * 256 + sw] = h;
        *(ushort4*)&BlP[r * 256 + sw] = l;
    }
}

// ---------------------------------------------------------------------------
// K1: t = x * s * rsqrt(s^2*colsum+eps), s from split-bf16 mod-GEMM.
// Pure async staging (64 KB LDS, no pad -- swizzle handles banks),
// ONE barrier, 24 MFMA, epilogue sums 8 colsum partials per thread.
// 256 thr, LDS 64 KB -> 2 blocks/CU.
// ---------------------------------------------------------------------------
__global__ __launch_bounds__(256, 2) void k1_mod(
    const unsigned short* __restrict__ AhP, const unsigned short* __restrict__ AlP,
    const unsigned short* __restrict__ BhP, const unsigned short* __restrict__ BlP,
    const float* __restrict__ csp,     // [8][512]
    const float* __restrict__ mod_b,   // [512]
    const float* __restrict__ x,       // [1024,512]
    unsigned short* __restrict__ t_bf) // [1024,512] bf16
{
    __shared__ unsigned short AhL[32 * 256], AlL[32 * 256];
    __shared__ unsigned short BhL[32 * 256], BlL[32 * 256];

    const int tid = threadIdx.x;
    const int n0 = blockIdx.x * 32;
    const int m0 = blockIdx.y * 32;
    const int lane = tid & 63, wv = tid >> 6;              // 4 waves
    const int wm = (wv >> 1) * 16, wn = (wv & 1) * 16;     // 2x2 wave grid
    const int lr = lane & 15, lq = lane >> 4;

    // ---- async stage: 16 issues/wave, 2 rows (1024B) per issue ----
    #pragma unroll
    for (int i = 0; i < 4; i++) {
        const int pr = wv * 8 + 2 * i;
        gload_lds16(AhP + (m0 + pr) * 256 + lane * 8, &AhL[pr * 256]);
        gload_lds16(AlP + (m0 + pr) * 256 + lane * 8, &AlL[pr * 256]);
        gload_lds16(BhP + (n0 + pr) * 256 + lane * 8, &BhL[pr * 256]);
        gload_lds16(BlP + (n0 + pr) * 256 + lane * 8, &BlL[pr * 256]);
    }

    // ---- prefetch epilogue operands (overlap with staging) ----
    const int gn = n0 + wn + lr;
    float xv[4];
    #pragma unroll
    for (int rr = 0; rr < 4; rr++)
        xv[rr] = x[(m0 + wm + lq * 4 + rr) * IN_DIMS + gn];
    float pp[8];
    #pragma unroll
    for (int p = 0; p < 8; p++)
        pp[p] = csp[p * 512 + gn];
    const float mb = mod_b[gn];

    __syncthreads();   // drains vmcnt (incl. global_load_lds)

    // ---- MFMA: 8 kk-steps, 3 MFMA each (hh, hl, lh) ----
    // swizzled read: chunk (ko>>3) XOR row&7; (wm/wn+lr)&7 == lr&7
    f32x4 acc = {};
    #pragma unroll
    for (int kk = 0; kk < 256; kk += 32) {
        const int ko = kk + lq * 8;
        const int sw = ((ko >> 3) ^ (lr & 7)) << 3;
        bf16x8 ah = *(bf16x8*)&AhL[(wm + lr) * 256 + sw];
        bf16x8 al = *(bf16x8*)&AlL[(wm + lr) * 256 + sw];
        bf16x8 bh = *(bf16x8*)&BhL[(wn + lr) * 256 + sw];
        bf16x8 bl = *(bf16x8*)&BlL[(wn + lr) * 256 + sw];
        acc = __builtin_amdgcn_mfma_f32_16x16x32_bf16(ah, bh, acc, 0, 0, 0);
        acc = __builtin_amdgcn_mfma_f32_16x16x32_bf16(ah, bl, acc, 0, 0, 0);
        acc = __builtin_amdgcn_mfma_f32_16x16x32_bf16(al, bh, acc, 0, 0, 0);
    }

    // ---- epilogue ----
    const float cs = ((pp[0] + pp[1]) + (pp[2] + pp[3]))
                   + ((pp[4] + pp[5]) + (pp[6] + pp[7]));
    // C/D layout: col = lane&15, row = (lane>>4)*4 + reg
    #pragma unroll
    for (int rr = 0; rr < 4; rr++) {
        const int gm = m0 + wm + lq * 4 + rr;
        const float s = acc[rr] + mb;
        const float tv = xv[rr] * s * rsqrtf(s * s * cs + EPS_F);
        t_bf[gm * IN_DIMS + gn] = f2bf(tv);
    }
}

// ---------------------------------------------------------------------------
// K2: out = t_bf @ wbf^T + bias (unchanged from round 4/5 verified version).
// ---------------------------------------------------------------------------
#define LP2 536   // 1072B rows (67x16B): rows step 12 banks -> 2-way = free
__global__ __launch_bounds__(256, 2) void k2_out(
    const unsigned short* __restrict__ t_bf, // [1024,512] bf16
    const unsigned short* __restrict__ wbf,  // [512,512]  bf16
    const float* __restrict__ bias,          // [512]
    float* __restrict__ out)                 // [1024,512]
{
    __shared__ unsigned short As[32 * LP2];
    __shared__ unsigned short Bs[32 * LP2];

    const int tid = threadIdx.x;
    const int n0 = blockIdx.x * 32;
    const int m0 = blockIdx.y * 32;
    const int lane = tid & 63, wv = tid >> 6;              // 4 waves
    const int wm = (wv >> 1) * 16, wn = (wv & 1) * 16;     // 2x2 wave grid
    const int lr = lane & 15, lq = lane >> 4;

    const float bv = bias[n0 + wn + lr];

    #pragma unroll
    for (int i = 0; i < 8; i++) {
        const int r = wv * 8 + i;
        gload_lds16(t_bf + (m0 + r) * IN_DIMS + lane * 8, &As[r * LP2]);
    }
    #pragma unroll
    for (int i = 0; i < 8; i++) {
        const int r = wv * 8 + i;
        gload_lds16(wbf + (n0 + r) * IN_DIMS + lane * 8, &Bs[r * LP2]);
    }
    __syncthreads();

    f32x4 acc = {};
    #pragma unroll
    for (int kk = 0; kk < 512; kk += 32) {
        const int ko = kk + lq * 8;
        bf16x8 a = *(bf16x8*)&As[(wm + lr) * LP2 + ko];
        bf16x8 b = *(bf16x8*)&Bs[(wn + lr) * LP2 + ko];
        acc = __builtin_amdgcn_mfma_f32_16x16x32_bf16(a, b, acc, 0, 0, 0);
    }

    {
        const int gn = n0 + wn + lr;
        #pragma unroll
        for (int rr = 0; rr < 4; rr++) {
            const int gm = m0 + wm + lq * 4 + rr;
            out[gm * OUT_DIMS + gn] = acc[rr] + bv;
        }
    }
}

extern "C" void kernel_launch(void* const* d_in, const int* in_sizes, int n_in,
                              void* d_out, int out_size, void* d_ws, size_t ws_size,
                              hipStream_t stream)
{
    const float* modulations = (const float*)d_in[0]; // [1024, 256]
    const float* x           = (const float*)d_in[1]; // [1024, 512]
    const float* weight      = (const float*)d_in[2]; // [512, 512]
    const float* bias        = (const float*)d_in[3]; // [512]
    const float* mod_w       = (const float*)d_in[4]; // [512, 256]
    const float* mod_b       = (const float*)d_in[5]; // [512]
    float* out = (float*)d_out;                       // [1024, 512]

    char* ws = (char*)d_ws;
    unsigned short* t_bf = (unsigned short*)(ws);
    unsigned short* wbf  = (unsigned short*)(ws + (1u << 20));
    unsigned short* AhP  = (unsigned short*)(ws + (3u << 19));   // 1.5 MB
    unsigned short* AlP  = (unsigned short*)(ws + (4u << 19));   // 2.0 MB
    unsigned short* BhP  = (unsigned short*)(ws + (5u << 19));   // 2.5 MB
    unsigned short* BlP  = (unsigned short*)(ws + (11u << 18));  // 2.75 MB
    float*          csp  = (float*)         (ws + (3u << 20));   // 3.0 MB

    k0_prep<<<dim3(768), 256, 0, stream>>>(
        weight, modulations, mod_w, wbf, AhP, AlP, BhP, BlP, csp);

    k1_mod<<<dim3(16, 32), 256, 0, stream>>>(
        AhP, AlP, BhP, BlP, csp, mod_b, x, t_bf);

    k2_out<<<dim3(16, 32), 256, 0, stream>>>(
        t_bf, wbf, bias, out);
}

// Round 7
// 74.916 us; speedup vs baseline: 1.0214x; 1.0214x over previous
//
#include <hip/hip_runtime.h>
#include <math.h>

#define B_DIM    1024
#define IN_DIMS  512
#define OUT_DIMS 512
#define MOD_DIM  256
#define EPS_F    1e-8f

typedef __attribute__((ext_vector_type(8))) short bf16x8;
typedef __attribute__((ext_vector_type(4))) float f32x4;

__device__ __forceinline__ unsigned short f2bf(float f) {
    union { float f; unsigned u; } c; c.f = f;
    unsigned r = c.u + 0x7fffu + ((c.u >> 16) & 1u);   // RNE
    return (unsigned short)(r >> 16);
}
__device__ __forceinline__ float bf2f(unsigned short h) {
    union { float f; unsigned u; } c; c.u = ((unsigned)h) << 16;
    return c.f;
}

// async 16B/lane global->LDS (wave covers 64*16B = 1024B = one unpadded row)
__device__ __forceinline__ void gload_lds16(const void* g, void* l) {
    __builtin_amdgcn_global_load_lds(
        (const __attribute__((address_space(1))) unsigned int*)g,
        (__attribute__((address_space(3))) unsigned int*)l, 16, 0, 0);
}

// ---------------------------------------------------------------------------
// FINAL (= round-4 best-measured config, 74.66 us):
// Two kernels; 32x32 tiles; 256 thr (4 waves); grid (16,32)=512 blocks;
// LDS ~70/67 KB -> 2 blocks/CU (launch_bounds(256,2)).
// k1: stage mods/mod_w as split hi/lo bf16 (hh+hl+lh MFMA = fp32-grade s),
//     colsum of weight cols in-block, demod epilogue -> t_bf; also converts
//     1 weight row/block -> wbf (bijection over [0,512)) for k2.
// k2: out = t_bf @ wbf^T + bias; both operands pre-converted bf16, staged
//     via async global_load_lds (half the bytes of fp32, zero convert VALU).
// Session evidence: fusion w/ sw-barrier +29us; occupancy 2x -0.5us; MLP
// reorder +0.6us; prep-split +1.8us. Byte-cuts were the only real lever.
// Window floor: 268MB poison fill at 82% HBM (~41us) + reset memsets
// (~15us) are harness-fixed; kernel share ~19us is at its launch+latency
// floor for this dependency structure (k2 needs full t, so two dispatches).
// ---------------------------------------------------------------------------
#define LP1 264   // 528B rows (33x16B): rows step 4 banks -> 2-way = free
#define LP2 536   // 1072B rows (67x16B): rows step 12 banks -> 2-way = free

__global__ __launch_bounds__(256, 2) void k1_mod(
    const float* __restrict__ mods,    // [1024,256]
    const float* __restrict__ mod_w,   // [512,256]
    const float* __restrict__ mod_b,   // [512]
    const float* __restrict__ weight,  // [512,512]
    const float* __restrict__ x,       // [1024,512]
    unsigned short* __restrict__ t_bf, // [1024,512] bf16
    unsigned short* __restrict__ wbf)  // [512,512]  bf16
{
    __shared__ unsigned short Ah[32 * LP1], Al[32 * LP1];   // 33.8 KB
    __shared__ unsigned short Bh[32 * LP1], Bl[32 * LP1];   // 33.8 KB
    __shared__ float4 csm[32][8];                           // 4 KB
    __shared__ float colsum_s[32];

    const int tid = threadIdx.x;
    const int n0 = blockIdx.x * 32;     // 16 n-tiles
    const int m0 = blockIdx.y * 32;     // 32 m-tiles
    const int lane = tid & 63, wv = tid >> 6;              // 4 waves
    const int wm = (wv >> 1) * 16, wn = (wv & 1) * 16;     // 2x2 wave grid
    const int lr = lane & 15, lq = lane >> 4;

    // ---- stage A (mods, 32x256): 8 float4/thread, split hi/lo ----
    #pragma unroll
    for (int i = 0; i < 8; i++) {
        const int id = tid + i * 256;
        const int r = id >> 6, c4 = id & 63;
        float4 v = *(const float4*)&mods[(m0 + r) * MOD_DIM + c4 * 4];
        ushort4 h, l;
        h.x = f2bf(v.x); l.x = f2bf(v.x - bf2f(h.x));
        h.y = f2bf(v.y); l.y = f2bf(v.y - bf2f(h.y));
        h.z = f2bf(v.z); l.z = f2bf(v.z - bf2f(h.z));
        h.w = f2bf(v.w); l.w = f2bf(v.w - bf2f(h.w));
        *(ushort4*)&Ah[r * LP1 + c4 * 4] = h;
        *(ushort4*)&Al[r * LP1 + c4 * 4] = l;
    }
    // ---- stage B (mod_w, 32x256): 8 float4/thread, split hi/lo ----
    #pragma unroll
    for (int i = 0; i < 8; i++) {
        const int id = tid + i * 256;
        const int r = id >> 6, c4 = id & 63;
        float4 v = *(const float4*)&mod_w[(n0 + r) * MOD_DIM + c4 * 4];
        ushort4 h, l;
        h.x = f2bf(v.x); l.x = f2bf(v.x - bf2f(h.x));
        h.y = f2bf(v.y); l.y = f2bf(v.y - bf2f(h.y));
        h.z = f2bf(v.z); l.z = f2bf(v.z - bf2f(h.z));
        h.w = f2bf(v.w); l.w = f2bf(v.w - bf2f(h.w));
        *(ushort4*)&Bh[r * LP1 + c4 * 4] = h;
        *(ushort4*)&Bl[r * LP1 + c4 * 4] = l;
    }

    // ---- weight fp32->bf16 prep for K2: 1 row/block (row = by*16+bx) ----
    // bijection over [0,512): every wbf row written exactly once.
    if (tid < 128) {
        const int row = blockIdx.y * 16 + blockIdx.x;
        float4 v = *(const float4*)&weight[row * IN_DIMS + tid * 4];
        ushort4 h;
        h.x = f2bf(v.x); h.y = f2bf(v.y); h.z = f2bf(v.z); h.w = f2bf(v.w);
        *(ushort4*)&wbf[row * IN_DIMS + tid * 4] = h;
    }

    // ---- prefetch epilogue x values (hide scattered-load latency) ----
    float xv[4];
    {
        const int gn = n0 + wn + lr;
        #pragma unroll
        for (int rr = 0; rr < 4; rr++) {
            const int gm = m0 + wm + lq * 4 + rr;
            xv[rr] = x[gm * IN_DIMS + gn];
        }
    }

    // ---- colsum for this block's 32 cols: 16 coalesced float4 rounds ----
    // summation tree: row = rr + 32*it, rr in [0,32), then linear 0..31 reduce
    {
        const int c4 = tid & 7, rr = tid >> 3;             // 32 row-groups x 8 f4-cols
        float4 acc = {0.f, 0.f, 0.f, 0.f};
        #pragma unroll
        for (int it = 0; it < 16; it++) {
            const int row = rr + 32 * it;
            float4 v = *(const float4*)&weight[row * IN_DIMS + n0 + c4 * 4];
            acc.x += v.x * v.x; acc.y += v.y * v.y;
            acc.z += v.z * v.z; acc.w += v.w * v.w;
        }
        csm[rr][c4] = acc;
    }
    __syncthreads();
    if (tid < 8) {
        float4 s = csm[0][tid];
        #pragma unroll
        for (int j = 1; j < 32; j++) {
            float4 v = csm[j][tid];
            s.x += v.x; s.y += v.y; s.z += v.z; s.w += v.w;
        }
        *(float4*)&colsum_s[tid * 4] = s;
    }

    // ---- MFMA: 8 kk-steps, 3 MFMA each (hh, hl, lh), 16x16 out/wave ----
    f32x4 acc = {};
    #pragma unroll
    for (int kk = 0; kk < 256; kk += 32) {
        const int ko = kk + lq * 8;
        bf16x8 ah = *(bf16x8*)&Ah[(wm + lr) * LP1 + ko];
        bf16x8 al = *(bf16x8*)&Al[(wm + lr) * LP1 + ko];
        bf16x8 bh = *(bf16x8*)&Bh[(wn + lr) * LP1 + ko];
        bf16x8 bl = *(bf16x8*)&Bl[(wn + lr) * LP1 + ko];
        acc = __builtin_amdgcn_mfma_f32_16x16x32_bf16(ah, bh, acc, 0, 0, 0);
        acc = __builtin_amdgcn_mfma_f32_16x16x32_bf16(ah, bl, acc, 0, 0, 0);
        acc = __builtin_amdgcn_mfma_f32_16x16x32_bf16(al, bh, acc, 0, 0, 0);
    }
    __syncthreads();   // colsum_s visibility for all waves

    // ---- epilogue: s -> t = x*s*rsqrt(s^2*colsum+eps) -> bf16 ----
    // C/D layout: col = lane&15, row = (lane>>4)*4 + reg
    {
        const int ln = wn + lr;
        const int gn = n0 + ln;
        const float cs = colsum_s[ln];
        const float mb = mod_b[gn];
        #pragma unroll
        for (int rr = 0; rr < 4; rr++) {
            const int gm = m0 + wm + lq * 4 + rr;
            const float s = acc[rr] + mb;
            const float tv = xv[rr] * s * rsqrtf(s * s * cs + EPS_F);
            t_bf[gm * IN_DIMS + gn] = f2bf(tv);
        }
    }
}

// ---------------------------------------------------------------------------
// K2: out = t_bf @ wbf^T + bias, both operands pre-converted bf16 (async
// global_load_lds staging only). 32x32 tile, 256 thr, 2 blocks/CU.
// ---------------------------------------------------------------------------
__global__ __launch_bounds__(256, 2) void k2_out(
    const unsigned short* __restrict__ t_bf, // [1024,512] bf16
    const unsigned short* __restrict__ wbf,  // [512,512]  bf16
    const float* __restrict__ bias,          // [512]
    float* __restrict__ out)                 // [1024,512]
{
    __shared__ unsigned short As[32 * LP2];   // 33.5 KB
    __shared__ unsigned short Bs[32 * LP2];   // 33.5 KB

    const int tid = threadIdx.x;
    const int n0 = blockIdx.x * 32;
    const int m0 = blockIdx.y * 32;
    const int lane = tid & 63, wv = tid >> 6;              // 4 waves
    const int wm = (wv >> 1) * 16, wn = (wv & 1) * 16;     // 2x2 wave grid
    const int lr = lane & 15, lq = lane >> 4;

    // bias prefetch (hide latency under staging)
    const float bv = bias[n0 + wn + lr];

    // ---- stage A (t_bf, 32x512 bf16): async, 8 rows/wave, 1 issue/row ----
    #pragma unroll
    for (int i = 0; i < 8; i++) {
        const int r = wv * 8 + i;
        gload_lds16(t_bf + (m0 + r) * IN_DIMS + lane * 8, &As[r * LP2]);
    }
    // ---- stage B (wbf, 32x512 bf16): async, 8 rows/wave ----
    #pragma unroll
    for (int i = 0; i < 8; i++) {
        const int r = wv * 8 + i;
        gload_lds16(wbf + (n0 + r) * IN_DIMS + lane * 8, &Bs[r * LP2]);
    }
    __syncthreads();   // drains vmcnt (incl. global_load_lds)

    f32x4 acc = {};
    #pragma unroll
    for (int kk = 0; kk < 512; kk += 32) {
        const int ko = kk + lq * 8;
        bf16x8 a = *(bf16x8*)&As[(wm + lr) * LP2 + ko];
        bf16x8 b = *(bf16x8*)&Bs[(wn + lr) * LP2 + ko];
        acc = __builtin_amdgcn_mfma_f32_16x16x32_bf16(a, b, acc, 0, 0, 0);
    }

    {
        const int gn = n0 + wn + lr;
        #pragma unroll
        for (int rr = 0; rr < 4; rr++) {
            const int gm = m0 + wm + lq * 4 + rr;
            out[gm * OUT_DIMS + gn] = acc[rr] + bv;
        }
    }
}

extern "C" void kernel_launch(void* const* d_in, const int* in_sizes, int n_in,
                              void* d_out, int out_size, void* d_ws, size_t ws_size,
                              hipStream_t stream)
{
    const float* modulations = (const float*)d_in[0]; // [1024, 256]
    const float* x           = (const float*)d_in[1]; // [1024, 512]
    const float* weight      = (const float*)d_in[2]; // [512, 512]
    const float* bias        = (const float*)d_in[3]; // [512]
    const float* mod_w       = (const float*)d_in[4]; // [512, 256]
    const float* mod_b       = (const float*)d_in[5]; // [512]
    float* out = (float*)d_out;                       // [1024, 512]

    unsigned short* t_bf = (unsigned short*)d_ws;                  // 1 MB
    unsigned short* wbf  = (unsigned short*)d_ws + (1024 * 512);   // 512 KB

    k1_mod<<<dim3(16, 32), 256, 0, stream>>>(
        modulations, mod_w, mod_b, weight, x, t_bf, wbf);

    k2_out<<<dim3(16, 32), 256, 0, stream>>>(
        t_bf, wbf, bias, out);
}